// Round 4
// baseline (458.103 us; speedup 1.0000x reference)
//
#include <hip/hip_runtime.h>
#include <math.h>

// Sizes (fixed for this problem)
#define NB   16
#define NCIN 512
#define NL   1024
#define NCOUT 1024
#define NK   5
#define NDW  512
#define NHW  196
#define NP   208   // HW padded to 13 n-tiles of 16
#define NPK  224   // HW padded to 7 k-chunks of 32

typedef unsigned short ushort_t;
typedef unsigned int uint_t;
typedef __attribute__((ext_vector_type(8))) short bf16x8;
typedef __attribute__((ext_vector_type(4))) float f32x4;

static __device__ __forceinline__ ushort_t f2bf(float f) {
  uint_t u = __builtin_bit_cast(uint_t, f);
  u += 0x7fff + ((u >> 16) & 1);  // round-to-nearest-even
  return (ushort_t)(u >> 16);
}
static __device__ __forceinline__ float bf2f(ushort_t u) {
  uint_t v = ((uint_t)u) << 16;
  return __builtin_bit_cast(float, v);
}

// ---------------------------------------------------------------------------
// K1: weight norm -> permuted bf16 weights.
// wperm[dk][co][ci] = bf16( g[co]/||v[co]|| * v[co][ci][dk] )
// ---------------------------------------------------------------------------
__global__ __launch_bounds__(256) void wnorm_kernel(
    const float* __restrict__ v, const float* __restrict__ g,
    ushort_t* __restrict__ wperm) {
  const int o = blockIdx.x;
  const float* vr = v + (size_t)o * (NCIN * NK);
  float s = 0.f;
  for (int j = threadIdx.x; j < NCIN * NK; j += 256) {
    float t = vr[j];
    s += t * t;
  }
  for (int off = 32; off; off >>= 1) s += __shfl_down(s, off, 64);
  __shared__ float red[4];
  __shared__ float scale_s;
  const int wid = threadIdx.x >> 6;
  if ((threadIdx.x & 63) == 0) red[wid] = s;
  __syncthreads();
  if (threadIdx.x == 0) {
    float tot = red[0] + red[1] + red[2] + red[3];
    scale_s = g[o] / sqrtf(tot);
  }
  __syncthreads();
  const float scale = scale_s;
#pragma unroll
  for (int dk = 0; dk < NK; ++dk) {
    for (int ci = threadIdx.x; ci < NCIN; ci += 256) {
      wperm[((size_t)dk * NCOUT + o) * NCIN + ci] = f2bf(vr[ci * NK + dk] * scale);
    }
  }
}

// ---------------------------------------------------------------------------
// K2a: transpose + bf16 convert:  xT[b][l][ci] = bf16(x[b][ci][l])
// ---------------------------------------------------------------------------
__global__ __launch_bounds__(256) void xpose_kernel(
    const float* __restrict__ x, ushort_t* __restrict__ xT) {
  const int b = blockIdx.z;
  const int ci0 = blockIdx.y * 64;
  const int l0 = blockIdx.x * 64;
  const int tid = threadIdx.x;
  __shared__ float t[64][65];
  const float* xb = x + ((size_t)b * NCIN + ci0) * NL + l0;
#pragma unroll
  for (int r = 0; r < 4; ++r) {
    int row = r * 16 + (tid >> 4);
    int col = (tid & 15) * 4;
    float4 v = *(const float4*)&xb[(size_t)row * NL + col];
    t[row][col + 0] = v.x; t[row][col + 1] = v.y;
    t[row][col + 2] = v.z; t[row][col + 3] = v.w;
  }
  __syncthreads();
  ushort_t* xo = xT + ((size_t)b * NL + l0) * NCIN + ci0;
#pragma unroll
  for (int r = 0; r < 4; ++r) {
    int lrow = r * 16 + (tid >> 4);
    int cic = (tid & 15) * 4;
    ushort4 o4;
    o4.x = f2bf(t[cic + 0][lrow]);
    o4.y = f2bf(t[cic + 1][lrow]);
    o4.z = f2bf(t[cic + 2][lrow]);
    o4.w = f2bf(t[cic + 3][lrow]);
    *(ushort4*)&xo[(size_t)lrow * NCIN + cic] = o4;
  }
}

// ---------------------------------------------------------------------------
// K-prep: fc1_w / fc2_w -> bf16 (both [512][512], row-major, k=last dim)
// ---------------------------------------------------------------------------
__global__ __launch_bounds__(256) void wcvt_kernel(
    const float* __restrict__ w1, const float* __restrict__ w2,
    ushort_t* __restrict__ w1bf, ushort_t* __restrict__ w2bf) {
  const int i = (blockIdx.x * 256 + threadIdx.x) * 4;
  {
    float4 v = *(const float4*)&w1[i];
    ushort4 o; o.x = f2bf(v.x); o.y = f2bf(v.y); o.z = f2bf(v.z); o.w = f2bf(v.w);
    *(ushort4*)&w1bf[i] = o;
  }
  {
    float4 v = *(const float4*)&w2[i];
    ushort4 o; o.x = f2bf(v.x); o.y = f2bf(v.y); o.z = f2bf(v.z); o.w = f2bf(v.w);
    *(ushort4*)&w2bf[i] = o;
  }
}

// ---------------------------------------------------------------------------
// K-prep: feat transforms + out_img passthrough.
//  fThi/fTlo[b][p][a] : split-bf16 transpose of feat (rows p>=196 zeroed)
//  fbf[b][a][p']      : bf16 feat, p' padded to 224 with zeros
// ---------------------------------------------------------------------------
__global__ __launch_bounds__(256) void ftrans_kernel(
    const float* __restrict__ feat, ushort_t* __restrict__ fThi,
    ushort_t* __restrict__ fTlo, ushort_t* __restrict__ fbf,
    float* __restrict__ out_img) {
  const int b = blockIdx.y;
  const int a0 = blockIdx.x * 64;
  const int tid = threadIdx.x;
  __shared__ float t[64][200];

  const float* fb_ = feat + ((size_t)b * NDW + a0) * NHW;
#pragma unroll
  for (int pp = 0; pp < 16; ++pp) {
    int row = pp * 4 + (tid >> 6);
#pragma unroll
    for (int cc = 0; cc < 4; ++cc) {
      int col = cc * 64 + (tid & 63);
      if (col < NHW) {
        float v = fb_[(size_t)row * NHW + col];
        t[row][col] = v;
        out_img[((size_t)b * NDW + a0 + row) * NHW + col] = v;  // passthrough output
      }
    }
  }
  __syncthreads();

  // fT writes: 208 p-rows x 64 a
  for (int pp = 0; pp < 13; ++pp) {
    int p = pp * 16 + (tid >> 4);
    int j = (tid & 15) * 4;
    ushort4 hi4, lo4;
#pragma unroll
    for (int k = 0; k < 4; ++k) {
      float v = (p < NHW) ? t[j + k][p] : 0.f;
      ushort_t h = f2bf(v);
      float lof = v - bf2f(h);
      ushort_t l = f2bf(lof);
      ((ushort_t*)&hi4)[k] = h;
      ((ushort_t*)&lo4)[k] = l;
    }
    size_t base = ((size_t)b * NP + p) * NDW + a0 + j;
    *(ushort4*)&fThi[base] = hi4;
    *(ushort4*)&fTlo[base] = lo4;
  }

  // fbf writes: 64 a-rows x 224 p
#pragma unroll
  for (int cc = 0; cc < 4; ++cc) {
    int col = cc * 64 + (tid & 63);
    if (col < NPK) {
#pragma unroll
      for (int rr = 0; rr < 16; ++rr) {
        int al = rr * 4 + (tid >> 6);
        float v = (col < NHW) ? t[al][col] : 0.f;
        fbf[((size_t)b * NDW + a0 + al) * NPK + col] = f2bf(v);
      }
    }
  }
}

// ---------------------------------------------------------------------------
// K2b: conv1d + bias + GLU via bf16 MFMA implicit GEMM.
// Writes hbfT[b][l][c] = bf16(h)
// ---------------------------------------------------------------------------
__global__ __launch_bounds__(256, 2) void conv_glu_mfma(
    const ushort_t* __restrict__ xT, const ushort_t* __restrict__ wperm,
    const float* __restrict__ conv_b, ushort_t* __restrict__ hbfT) {
  const int b  = blockIdx.z;
  const int c0 = blockIdx.y * 128;
  const int l0 = blockIdx.x * 128;
  const int tid = threadIdx.x;
  const int wid = tid >> 6;
  const int lane = tid & 63;
  const int wl = wid & 1;
  const int wc = wid >> 1;
  const int quad = lane >> 4;
  const int l16 = lane & 15;

  __shared__ ushort_t lx[128][72];
  __shared__ ushort_t lw[256][72];

  f32x4 accA[4][4], accB[4][4];
#pragma unroll
  for (int mt = 0; mt < 4; ++mt)
#pragma unroll
    for (int nt = 0; nt < 4; ++nt) {
      accA[mt][nt] = (f32x4){0.f, 0.f, 0.f, 0.f};
      accB[mt][nt] = (f32x4){0.f, 0.f, 0.f, 0.f};
    }

  const ushort_t* xTb = xT + (size_t)b * NL * NCIN;

  for (int dk = 0; dk < NK; ++dk) {
    const int lbase = l0 + dk - 4;
    const ushort_t* wpb = wperm + (size_t)dk * NCOUT * NCIN;
    for (int ci0 = 0; ci0 < NCIN; ci0 += 64) {
      __syncthreads();
#pragma unroll
      for (int it = 0; it < 4; ++it) {
        int t = tid + it * 256;
        int r = t >> 3, seg = t & 7;
        int gl = lbase + r;
        uint4 v = make_uint4(0u, 0u, 0u, 0u);
        if (gl >= 0)
          v = *(const uint4*)(xTb + (size_t)gl * NCIN + ci0 + seg * 8);
        *(uint4*)&lx[r][seg * 8] = v;
      }
#pragma unroll
      for (int it = 0; it < 8; ++it) {
        int t = tid + it * 256;
        int r = t >> 3, seg = t & 7;
        int co = (it < 4) ? (c0 + r) : (384 + c0 + r);
        uint4 v = *(const uint4*)(wpb + (size_t)co * NCIN + ci0 + seg * 8);
        *(uint4*)&lw[r][seg * 8] = v;
      }
      __syncthreads();
#pragma unroll
      for (int ks = 0; ks < 2; ++ks) {
        bf16x8 af[4];
#pragma unroll
        for (int mt = 0; mt < 4; ++mt)
          af[mt] = *(const bf16x8*)&lx[wl * 64 + mt * 16 + l16][ks * 32 + quad * 8];
#pragma unroll
        for (int nt = 0; nt < 4; ++nt) {
          bf16x8 bfa = *(const bf16x8*)&lw[wc * 64 + nt * 16 + l16][ks * 32 + quad * 8];
          bf16x8 bfb = *(const bf16x8*)&lw[128 + wc * 64 + nt * 16 + l16][ks * 32 + quad * 8];
#pragma unroll
          for (int mt = 0; mt < 4; ++mt) {
            accA[mt][nt] = __builtin_amdgcn_mfma_f32_16x16x32_bf16(af[mt], bfa, accA[mt][nt], 0, 0, 0);
            accB[mt][nt] = __builtin_amdgcn_mfma_f32_16x16x32_bf16(af[mt], bfb, accB[mt][nt], 0, 0, 0);
          }
        }
      }
    }
  }

#pragma unroll
  for (int nt = 0; nt < 4; ++nt) {
    const int co = c0 + wc * 64 + nt * 16 + l16;
    const float ba = conv_b[co];
    const float bb = conv_b[co + 512];
#pragma unroll
    for (int mt = 0; mt < 4; ++mt) {
      const int l = l0 + wl * 64 + mt * 16 + quad * 4;
      f32x4 a4 = accA[mt][nt];
      f32x4 b4 = accB[mt][nt];
#pragma unroll
      for (int r = 0; r < 4; ++r) {
        float aa = a4[r] + ba, bg = b4[r] + bb;
        float hv = aa * (1.f / (1.f + __expf(-bg)));
        hbfT[((size_t)b * NL + l + r) * NDW + co] = f2bf(hv);
      }
    }
  }
}

// ---------------------------------------------------------------------------
// K3: fc1 MFMA.  q[l][a] = sum_c hbfT[l][c]*w1bf[a][c] + b[a] + we[l][a]
// Writes split q (qhi/qlo) and also copies we -> out_we (fused passthrough).
// ---------------------------------------------------------------------------
__global__ __launch_bounds__(256, 2) void fc1_mfma(
    const ushort_t* __restrict__ hbfT, const ushort_t* __restrict__ w1bf,
    const float* __restrict__ fb, const float* __restrict__ we,
    ushort_t* __restrict__ qhi, ushort_t* __restrict__ qlo,
    float* __restrict__ out_we) {
  const int b  = blockIdx.z;
  const int a0 = blockIdx.y * 128;
  const int l0 = blockIdx.x * 128;
  const int tid = threadIdx.x;
  const int wid = tid >> 6;
  const int lane = tid & 63;
  const int wl = wid & 1;
  const int wc = wid >> 1;
  const int quad = lane >> 4;
  const int l16 = lane & 15;

  __shared__ ushort_t la[128][72];
  __shared__ ushort_t lb[128][72];

  f32x4 acc[4][4];
#pragma unroll
  for (int mt = 0; mt < 4; ++mt)
#pragma unroll
    for (int nt = 0; nt < 4; ++nt) acc[mt][nt] = (f32x4){0.f, 0.f, 0.f, 0.f};

  const ushort_t* hb = hbfT + (size_t)b * NL * NDW;

  for (int c0 = 0; c0 < NDW; c0 += 64) {
    __syncthreads();
#pragma unroll
    for (int it = 0; it < 4; ++it) {
      int t = tid + it * 256;
      int r = t >> 3, seg = t & 7;
      *(uint4*)&la[r][seg * 8] = *(const uint4*)(hb + (size_t)(l0 + r) * NDW + c0 + seg * 8);
    }
#pragma unroll
    for (int it = 0; it < 4; ++it) {
      int t = tid + it * 256;
      int r = t >> 3, seg = t & 7;
      *(uint4*)&lb[r][seg * 8] = *(const uint4*)(w1bf + (size_t)(a0 + r) * NDW + c0 + seg * 8);
    }
    __syncthreads();
#pragma unroll
    for (int ks = 0; ks < 2; ++ks) {
      bf16x8 af[4];
#pragma unroll
      for (int mt = 0; mt < 4; ++mt)
        af[mt] = *(const bf16x8*)&la[wl * 64 + mt * 16 + l16][ks * 32 + quad * 8];
#pragma unroll
      for (int nt = 0; nt < 4; ++nt) {
        bf16x8 bf = *(const bf16x8*)&lb[wc * 64 + nt * 16 + l16][ks * 32 + quad * 8];
#pragma unroll
        for (int mt = 0; mt < 4; ++mt)
          acc[mt][nt] = __builtin_amdgcn_mfma_f32_16x16x32_bf16(af[mt], bf, acc[mt][nt], 0, 0, 0);
      }
    }
  }

#pragma unroll
  for (int nt = 0; nt < 4; ++nt) {
    const int a = a0 + wc * 64 + nt * 16 + l16;
    const float bias = fb[a];
#pragma unroll
    for (int mt = 0; mt < 4; ++mt) {
      const int l = l0 + wl * 64 + mt * 16 + quad * 4;
#pragma unroll
      for (int r = 0; r < 4; ++r) {
        size_t idx = ((size_t)b * NL + l + r) * NDW + a;
        float wev = we[idx];
        out_we[idx] = wev;                       // fused passthrough
        float qv = acc[mt][nt][r] + bias + wev;
        ushort_t h = f2bf(qv);
        float lof = qv - bf2f(h);
        qhi[idx] = h;
        qlo[idx] = f2bf(lof);
      }
    }
  }
}

// ---------------------------------------------------------------------------
// K4: FUSED attention: scores (3-pass split-bf16) + softmax + attn write + ctx.
// Block: 64 q-rows, 4 waves in 2x2 (wm: row-half, wn: col-split).
// Phase A: S[64][208] over K=512 (16 kc), f staged via VGPR-prefetch -> LDS.
// Softmax: cross-wave (wn) exchange via rmx/rsm LDS.
// P -> as[64][232] bf16 (A-layout via LDS); Phase B: ctx[64][512] over K=224.
// Writes ctx_bf (aliases qhi: block writes exactly the rows only it read).
// ---------------------------------------------------------------------------
__global__ __launch_bounds__(256) void attn_fused(
    const ushort_t* __restrict__ qhi, const ushort_t* __restrict__ qlo,
    const ushort_t* __restrict__ fThi, const ushort_t* __restrict__ fTlo,
    const ushort_t* __restrict__ fbf,
    float* __restrict__ out_attn, ushort_t* __restrict__ ctx_bf) {
  const int b  = blockIdx.y;
  const int l0 = blockIdx.x * 64;
  const int tid = threadIdx.x;
  const int wid = tid >> 6;
  const int lane = tid & 63;
  const int quad = lane >> 4;
  const int l16 = lane & 15;
  const int wm = wid & 1;    // row half (32 l each)
  const int wn = wid >> 1;   // col split

  // LDS union: fh[208][40] fl[208][40] (phase A) / as_[64][232] fbt[64][232] (phase B)
  // as_ aliases fh (+part of fl): dead by then. fbt at +16640 is disjoint from as_.
  __shared__ ushort_t smem[31488];   // 62976 B
  ushort_t* fh  = smem;
  ushort_t* fl  = smem + 8320;
  ushort_t* as_ = smem;
  ushort_t* fbt = smem + 16640;
  __shared__ float rmx[64][2];
  __shared__ float rsm[64][2];

  const int NT = wn ? 6 : 7;
  const int ntbase = wn ? 7 : 0;

  f32x4 acc[2][7];
#pragma unroll
  for (int mt = 0; mt < 2; ++mt)
#pragma unroll
    for (int nt = 0; nt < 7; ++nt) acc[mt][nt] = (f32x4){0.f, 0.f, 0.f, 0.f};

  const int frow = tid >> 2;          // 0..63 (+ it*64)
  const int fseg = (tid & 3) * 8;

  // ---- phase A ----
  uint4 pfh[4], pfl[4];
#pragma unroll
  for (int it = 0; it < 4; ++it) {
    int r = it * 64 + frow;
    if (r < NP) {
      size_t src = ((size_t)b * NP + r) * NDW + fseg;
      pfh[it] = *(const uint4*)(fThi + src);
      pfl[it] = *(const uint4*)(fTlo + src);
    }
  }

  for (int kc = 0; kc < 16; ++kc) {
    __syncthreads();
#pragma unroll
    for (int it = 0; it < 4; ++it) {
      int r = it * 64 + frow;
      if (r < NP) {
        *(uint4*)&fh[r * 40 + fseg] = pfh[it];
        *(uint4*)&fl[r * 40 + fseg] = pfl[it];
      }
    }
    __syncthreads();
    if (kc < 15) {
#pragma unroll
      for (int it = 0; it < 4; ++it) {
        int r = it * 64 + frow;
        if (r < NP) {
          size_t src = ((size_t)b * NP + r) * NDW + (kc + 1) * 32 + fseg;
          pfh[it] = *(const uint4*)(fThi + src);
          pfl[it] = *(const uint4*)(fTlo + src);
        }
      }
    }
    // q A-frags straight from global
    bf16x8 ah[2], alo[2];
#pragma unroll
    for (int mt = 0; mt < 2; ++mt) {
      int lq = l0 + wm * 32 + mt * 16 + l16;
      size_t base = ((size_t)b * NL + lq) * NDW + kc * 32 + quad * 8;
      ah[mt]  = *(const bf16x8*)(qhi + base);
      alo[mt] = *(const bf16x8*)(qlo + base);
    }
#pragma unroll
    for (int ntl = 0; ntl < 7; ++ntl) {
      if (ntl >= NT) break;
      int ntg = ntbase + ntl;
      bf16x8 bh = *(const bf16x8*)&fh[(ntg * 16 + l16) * 40 + quad * 8];
      bf16x8 bl = *(const bf16x8*)&fl[(ntg * 16 + l16) * 40 + quad * 8];
#pragma unroll
      for (int mt = 0; mt < 2; ++mt) {
        acc[mt][ntl] = __builtin_amdgcn_mfma_f32_16x16x32_bf16(ah[mt],  bh, acc[mt][ntl], 0, 0, 0);
        acc[mt][ntl] = __builtin_amdgcn_mfma_f32_16x16x32_bf16(alo[mt], bh, acc[mt][ntl], 0, 0, 0);
        acc[mt][ntl] = __builtin_amdgcn_mfma_f32_16x16x32_bf16(ah[mt],  bl, acc[mt][ntl], 0, 0, 0);
      }
    }
  }

  // ---- softmax (cross-wn via LDS) ----
  // D layout: row = wm*32 + mt*16 + quad*4 + r, col p = ntg*16 + l16
#pragma unroll
  for (int mt = 0; mt < 2; ++mt)
#pragma unroll
    for (int r = 0; r < 4; ++r) {
      float m = -3e38f;
#pragma unroll
      for (int ntl = 0; ntl < 7; ++ntl) {
        if (ntl >= NT) break;
        bool valid = !(wn == 1 && ntl == 5 && l16 >= 4);  // ntg==12, p>=196
        if (valid) m = fmaxf(m, acc[mt][ntl][r]);
      }
#pragma unroll
      for (int off = 1; off < 16; off <<= 1) m = fmaxf(m, __shfl_xor(m, off, 16));
      if (l16 == 0) rmx[wm * 32 + mt * 16 + quad * 4 + r][wn] = m;
    }
  __syncthreads();
  float inv_[2][4];
#pragma unroll
  for (int mt = 0; mt < 2; ++mt)
#pragma unroll
    for (int r = 0; r < 4; ++r) {
      int row = wm * 32 + mt * 16 + quad * 4 + r;
      float g = fmaxf(rmx[row][0], rmx[row][1]);
      float s = 0.f;
#pragma unroll
      for (int ntl = 0; ntl < 7; ++ntl) {
        if (ntl >= NT) break;
        bool valid = !(wn == 1 && ntl == 5 && l16 >= 4);
        float e = valid ? __expf(acc[mt][ntl][r] - g) : 0.f;
        acc[mt][ntl][r] = e;
        s += e;
      }
#pragma unroll
      for (int off = 1; off < 16; off <<= 1) s += __shfl_xor(s, off, 16);
      if (l16 == 0) rsm[row][wn] = s;
    }
  __syncthreads();
  // attn out + P into as_ (bf16, A-layout source)
#pragma unroll
  for (int mt = 0; mt < 2; ++mt)
#pragma unroll
    for (int r = 0; r < 4; ++r) {
      int row = wm * 32 + mt * 16 + quad * 4 + r;
      float inv = 1.f / (rsm[row][0] + rsm[row][1]);
      inv_[mt][r] = inv;
      float* ao = out_attn + ((size_t)b * NL + l0 + row) * NHW;
#pragma unroll
      for (int ntl = 0; ntl < 7; ++ntl) {
        if (ntl >= NT) break;
        int p = (ntbase + ntl) * 16 + l16;
        float vv = acc[mt][ntl][r] * inv;
        as_[row * 232 + p] = f2bf(vv);
        if (p < NHW) ao[p] = vv;
      }
    }
  (void)inv_;
  // zero as_ cols [208,224) (read by kc=6 of phase B)
  {
    int row = tid >> 2;
    int col = 208 + (tid & 3) * 4;
    ushort4 z4; z4.x = 0; z4.y = 0; z4.z = 0; z4.w = 0;
    *(ushort4*)&as_[row * 232 + col] = z4;
  }
  __syncthreads();

  // ---- phase B: ctx = P(64x224) * fbf^T(224x512), chunks of 64 a ----
  bf16x8 af[2][7];
#pragma unroll
  for (int mt = 0; mt < 2; ++mt)
#pragma unroll
    for (int kc = 0; kc < 7; ++kc)
      af[mt][kc] = *(const bf16x8*)&as_[(wm * 32 + mt * 16 + l16) * 232 + kc * 32 + quad * 8];

  for (int ac = 0; ac < 8; ++ac) {
    const int ac0 = ac * 64;
    __syncthreads();
#pragma unroll
    for (int it = 0; it < 7; ++it) {
      int sg = it * 4 + (tid & 3);
      *(uint4*)&fbt[frow * 232 + sg * 8] =
          *(const uint4*)(fbf + ((size_t)b * NDW + ac0 + frow) * NPK + sg * 8);
    }
    __syncthreads();
    f32x4 c2[2][2];
#pragma unroll
    for (int mt = 0; mt < 2; ++mt)
#pragma unroll
      for (int j2 = 0; j2 < 2; ++j2) c2[mt][j2] = (f32x4){0.f, 0.f, 0.f, 0.f};
#pragma unroll
    for (int kc = 0; kc < 7; ++kc) {
      bf16x8 bf0 = *(const bf16x8*)&fbt[((wn * 2 + 0) * 16 + l16) * 232 + kc * 32 + quad * 8];
      bf16x8 bf1 = *(const bf16x8*)&fbt[((wn * 2 + 1) * 16 + l16) * 232 + kc * 32 + quad * 8];
#pragma unroll
      for (int mt = 0; mt < 2; ++mt) {
        c2[mt][0] = __builtin_amdgcn_mfma_f32_16x16x32_bf16(af[mt][kc], bf0, c2[mt][0], 0, 0, 0);
        c2[mt][1] = __builtin_amdgcn_mfma_f32_16x16x32_bf16(af[mt][kc], bf1, c2[mt][1], 0, 0, 0);
      }
    }
#pragma unroll
    for (int mt = 0; mt < 2; ++mt)
#pragma unroll
      for (int j2 = 0; j2 < 2; ++j2) {
        int a = ac0 + (wn * 2 + j2) * 16 + l16;
#pragma unroll
        for (int r = 0; r < 4; ++r) {
          int l = l0 + wm * 32 + mt * 16 + quad * 4 + r;
          ctx_bf[((size_t)b * NL + l) * NDW + a] = f2bf(c2[mt][j2][r]);
        }
      }
  }
}

// ---------------------------------------------------------------------------
// K5: fc2 MFMA.  out[c][l] = sum_a w2bf[c][a]*ctx_bf[l][a] + fb2[c] + h + x
// ---------------------------------------------------------------------------
__global__ __launch_bounds__(256, 2) void fc2_mfma(
    const ushort_t* __restrict__ w2bf, const ushort_t* __restrict__ ctx_bf,
    const float* __restrict__ fb2, const ushort_t* __restrict__ hbfT,
    const float* __restrict__ x, float* __restrict__ out0) {
  const int b  = blockIdx.z;
  const int c0 = blockIdx.y * 128;
  const int l0 = blockIdx.x * 128;
  const int tid = threadIdx.x;
  const int wid = tid >> 6;
  const int lane = tid & 63;
  const int wl = wid & 1;
  const int wc = wid >> 1;
  const int quad = lane >> 4;
  const int l16 = lane & 15;

  __shared__ ushort_t la[128][72];
  __shared__ ushort_t lb[128][72];

  f32x4 acc[4][4];
#pragma unroll
  for (int mt = 0; mt < 4; ++mt)
#pragma unroll
    for (int nt = 0; nt < 4; ++nt) acc[mt][nt] = (f32x4){0.f, 0.f, 0.f, 0.f};

  for (int a0 = 0; a0 < NDW; a0 += 64) {
    __syncthreads();
#pragma unroll
    for (int it = 0; it < 4; ++it) {
      int t = tid + it * 256;
      int r = t >> 3, seg = t & 7;
      *(uint4*)&la[r][seg * 8] = *(const uint4*)(w2bf + (size_t)(c0 + r) * NDW + a0 + seg * 8);
    }
#pragma unroll
    for (int it = 0; it < 4; ++it) {
      int t = tid + it * 256;
      int r = t >> 3, seg = t & 7;
      *(uint4*)&lb[r][seg * 8] =
          *(const uint4*)(ctx_bf + ((size_t)b * NL + l0 + r) * NDW + a0 + seg * 8);
    }
    __syncthreads();
#pragma unroll
    for (int ks = 0; ks < 2; ++ks) {
      bf16x8 af[4];
#pragma unroll
      for (int mt = 0; mt < 4; ++mt)
        af[mt] = *(const bf16x8*)&la[wl * 64 + mt * 16 + l16][ks * 32 + quad * 8];
#pragma unroll
      for (int nt = 0; nt < 4; ++nt) {
        bf16x8 bf = *(const bf16x8*)&lb[wc * 64 + nt * 16 + l16][ks * 32 + quad * 8];
#pragma unroll
        for (int mt = 0; mt < 4; ++mt)
          acc[mt][nt] = __builtin_amdgcn_mfma_f32_16x16x32_bf16(af[mt], bf, acc[mt][nt], 0, 0, 0);
      }
    }
  }

#pragma unroll
  for (int mt = 0; mt < 4; ++mt) {
    const int cb = c0 + wl * 64 + mt * 16 + quad * 4;
    float4 bias4 = *(const float4*)&fb2[cb];
#pragma unroll
    for (int nt = 0; nt < 4; ++nt) {
      const int l = l0 + wc * 64 + nt * 16 + l16;
      ushort4 h4 = *(const ushort4*)&hbfT[((size_t)b * NL + l) * NDW + cb];
      const float bias[4] = {bias4.x, bias4.y, bias4.z, bias4.w};
      const ushort_t hs[4] = {h4.x, h4.y, h4.z, h4.w};
#pragma unroll
      for (int r = 0; r < 4; ++r) {
        size_t idx = ((size_t)b * NDW + cb + r) * NL + l;
        out0[idx] = acc[mt][nt][r] + bias[r] + bf2f(hs[r]) + x[idx];
      }
    }
  }
}

// ---------------------------------------------------------------------------
extern "C" void kernel_launch(void* const* d_in, const int* in_sizes, int n_in,
                              void* d_out, int out_size, void* d_ws, size_t ws_size,
                              hipStream_t stream) {
  const float* x      = (const float*)d_in[0];
  const float* we     = (const float*)d_in[1];
  const float* img    = (const float*)d_in[2];
  const float* conv_v = (const float*)d_in[4];
  const float* conv_g = (const float*)d_in[5];
  const float* conv_b = (const float*)d_in[6];
  const float* fc1_w  = (const float*)d_in[7];
  const float* fc1_b  = (const float*)d_in[8];
  const float* fc2_w  = (const float*)d_in[9];
  const float* fc2_b  = (const float*)d_in[10];

  float* out0     = (float*)d_out;          // (16,512,1024)
  float* out_we   = out0 + 8388608;         // (16,1024,512)
  float* out_img  = out_we + 8388608;       // (16,512,14,14)
  float* out_attn = out_img + 1605632;      // (16,1024,196)

  // Workspace layout (ushort units).
  ushort_t* wsu = (ushort_t*)d_ws;
  ushort_t* qhi   = wsu;                    // 8,388,608   [fc1 -> attn]
  ushort_t* qlo   = wsu + 8388608;          // 8,388,608   [fc1 -> attn]
  ushort_t* wperm = wsu;                    // 2,621,440   [prep alias of qhi]
  ushort_t* xT    = wsu + 2621440;          // 8,388,608   [prep alias]
  ushort_t* ctx_b = wsu;                    // aliases qhi: attn_fused block writes
                                            // exactly the q rows only it reads
  ushort_t* hbfT  = wsu + 16777216;         // 8,388,608   [conv -> fc1/fc2]
  ushort_t* w1bf  = wsu + 25165824;         // 262,144
  ushort_t* w2bf  = wsu + 25165824 + 262144;// 262,144
  ushort_t* fThi  = wsu + 25690112;         // 1,703,936
  ushort_t* fTlo  = wsu + 27394048;         // 1,703,936
  ushort_t* fbf   = wsu + 29097984;         // 1,835,008  -> ends 30,932,992 (61.9MB)

  wnorm_kernel<<<dim3(NCOUT), 256, 0, stream>>>(conv_v, conv_g, wperm);
  xpose_kernel<<<dim3(16, 8, NB), 256, 0, stream>>>(x, xT);
  wcvt_kernel<<<dim3(256), 256, 0, stream>>>(fc1_w, fc2_w, w1bf, w2bf);
  ftrans_kernel<<<dim3(8, NB), 256, 0, stream>>>(img, fThi, fTlo, fbf, out_img);

  conv_glu_mfma<<<dim3(8, 4, NB), 256, 0, stream>>>(xT, wperm, conv_b, hbfT);
  fc1_mfma<<<dim3(8, 4, NB), 256, 0, stream>>>(hbfT, w1bf, fc1_b, we, qhi, qlo, out_we);
  attn_fused<<<dim3(16, NB), 256, 0, stream>>>(qhi, qlo, fThi, fTlo, fbf,
                                               out_attn, ctx_b);
  fc2_mfma<<<dim3(8, 4, NB), 256, 0, stream>>>(w2bf, ctx_b, fc2_b, hbfT, x, out0);
}